// Round 7
// baseline (110.871 us; speedup 1.0000x reference)
//
#include <hip/hip_runtime.h>

#define DIMX 100
#define BATCH 131072
#define BUFW 108          // u16 stride: 216 B/row; all u16x4 accesses 8B-aligned

typedef __bf16 bf16x8 __attribute__((ext_vector_type(8)));
typedef __bf16 bf16x4 __attribute__((ext_vector_type(4)));
typedef float  f32x4  __attribute__((ext_vector_type(4)));

// ---- kernel 1: convert A (100x100 fp32) to zero-padded bf16 [112][128] in ws ----
__global__ void conv_A(const float* __restrict__ A, __bf16* __restrict__ ws) {
    int i = blockIdx.x * 256 + threadIdx.x;          // 112*128 = 14336
    if (i < 112 * 128) {
        int j = i >> 7, k = i & 127;
        float v = (j < DIMX && k < DIMX) ? A[j * DIMX + k] : 0.0f;
        ws[i] = (__bf16)v;
    }
}

// ---- main kernel: barrier-free; per-wave private bf16 LDS tile (16 rows) ----
// (256,4): cap 128 VGPR. R5's (256,8) collapsed VGPR->32 and killed MLP;
// plain bounds gave 52 VGPR / ~8 outstanding loads. Here we explicitly stage
// all 21 phase-A loads (X/E/W, 84 VGPR) + 8 afrag loads before any compute.
template <bool USE_WS>
__global__ __launch_bounds__(256, 4) void ca_main(
    const float* __restrict__ state, const float* __restrict__ Amat,
    const __bf16* __restrict__ Bws, const float* __restrict__ target,
    float* __restrict__ out)
{
    __shared__ __align__(16) __bf16 buf[4][16 * BUFW];  // 13824 B/block

    const int tid = threadIdx.x;
    const int wave = tid >> 6, lane = tid & 63;
    __bf16* __restrict__ wbuf = buf[wave];
    const long r0 = (long)blockIdx.x * 64 + wave * 16;   // wave's first row

    // ---- load stage: issue ALL HBM loads for this wave up front ----
    f32x4 X[7], E[7], W[7];                 // phase-A operands, static indices only
#pragma unroll
    for (int it = 0; it < 7; ++it) {
        int i = lane + it * 64;
        if (i < 400) {                      // 16 rows x 25 quads
            int row = i / 25, c4 = i - row * 25, j0 = c4 * 4;
            const float* rp = state + (r0 + row) * 400;
            X[it] = *reinterpret_cast<const f32x4*>(rp + j0);
            E[it] = *reinterpret_cast<const f32x4*>(rp + DIMX + j0);
            W[it] = *reinterpret_cast<const f32x4*>(rp + 3 * DIMX + j0);
        }
    }
    // afrag x-loads (fragment order), issued alongside
    const int fr = lane & 15, h = lane >> 4;
    const float* sp = state + (r0 + fr) * 400;
    f32x4 XA[4], XB[4];                     // kt=0..3, k0 = kt*32 + h*8
#pragma unroll
    for (int kt = 0; kt < 4; ++kt) {
        int k0 = kt * 32 + h * 8;
        if (k0 < DIMX) {
            XA[kt] = *reinterpret_cast<const f32x4*>(sp + k0);
            XB[kt] = *reinterpret_cast<const f32x4*>(sp + k0 + 4);
        }
    }

    // ---- Phase A compute: base = -x + u*s -> LDS bf16 ----
#pragma unroll
    for (int it = 0; it < 7; ++it) {
        int i = lane + it * 64;
        if (i < 400) {
            int row = i / 25, c4 = i - row * 25, j0 = c4 * 4;
            f32x4 t = *reinterpret_cast<const f32x4*>(target + j0);  // L1-hot
            bf16x4 b;
#pragma unroll
            for (int q = 0; q < 4; ++q) {
                float u  = W[it][q] * (X[it][q] + E[it][q] - t[q]);
                float x2 = X[it][q] * X[it][q];
                float s  = x2 * __builtin_amdgcn_rcpf(1.0f + x2);
                b[q] = (__bf16)fmaf(u, s, -X[it][q]);
            }
            *reinterpret_cast<bf16x4*>(&wbuf[row * BUFW + j0]) = b;
        }
    }

    // ---- afrag: s = x^2/(1+x^2) in fragment layout ----
    bf16x8 afrag[4];
#pragma unroll
    for (int kt = 0; kt < 4; ++kt) {
        int k0 = kt * 32 + h * 8;
        bf16x8 f = {};
        if (k0 < DIMX) {
#pragma unroll
            for (int e = 0; e < 8; ++e) {
                float x = (e < 4) ? XA[kt][e] : XB[kt][e - 4];
                float x2 = x * x;
                float s = x2 * __builtin_amdgcn_rcpf(1.0f + x2);
                f[e] = (k0 + e < DIMX) ? (__bf16)s : (__bf16)0.0f;
            }
        }
        afrag[kt] = f;
    }

    // ---- MFMA over 7 N-tiles; epilogue: wbuf[row][j] = bf16(base + acc) ----
#pragma unroll
    for (int n = 0; n < 7; ++n) {
        f32x4 acc = {0.f, 0.f, 0.f, 0.f};
#pragma unroll
        for (int kt = 0; kt < 4; ++kt) {
            bf16x8 bf;
            if constexpr (USE_WS) {
                bf = *reinterpret_cast<const bf16x8*>(
                    Bws + (n * 16 + fr) * 128 + kt * 32 + h * 8);
            } else {
                int jj = n * 16 + fr;
#pragma unroll
                for (int e = 0; e < 8; ++e) {
                    int k = kt * 32 + h * 8 + e;
                    float v = (jj < DIMX && k < DIMX) ? Amat[jj * DIMX + k] : 0.0f;
                    bf[e] = (__bf16)v;
                }
            }
            acc = __builtin_amdgcn_mfma_f32_16x16x32_bf16(afrag[kt], bf, acc, 0, 0, 0);
        }
        int j = n * 16 + fr;
        if (j < DIMX) {
#pragma unroll
            for (int q = 0; q < 4; ++q) {
                int idx = (h * 4 + q) * BUFW + j;
                wbuf[idx] = (__bf16)((float)wbuf[idx] + acc[q]);
            }
        }
    }

    // ---- Phase B: contiguous nontemporal float4 writes of [dx,-dx,0,0] ----
#pragma unroll
    for (int it = 0; it < 25; ++it) {
        int i = lane + it * 64;                          // 16 rows x 100 quads
        int row = i / 100, c4 = i - row * 100;
        f32x4 v;
        if (c4 < 25) {
            bf16x4 d = *reinterpret_cast<const bf16x4*>(&wbuf[row * BUFW + c4 * 4]);
            v = f32x4{(float)d[0], (float)d[1], (float)d[2], (float)d[3]};
        } else if (c4 < 50) {
            bf16x4 d = *reinterpret_cast<const bf16x4*>(&wbuf[row * BUFW + c4 * 4 - DIMX]);
            v = f32x4{-(float)d[0], -(float)d[1], -(float)d[2], -(float)d[3]};
        } else {
            v = f32x4{0.f, 0.f, 0.f, 0.f};
        }
        __builtin_nontemporal_store(v,
            reinterpret_cast<f32x4*>(&out[(r0 + row) * 400 + c4 * 4]));
    }
}

extern "C" void kernel_launch(void* const* d_in, const int* in_sizes, int n_in,
                              void* d_out, int out_size, void* d_ws, size_t ws_size,
                              hipStream_t stream) {
    const float* state  = (const float*)d_in[0];
    const float* Amat   = (const float*)d_in[1];
    const float* target = (const float*)d_in[2];
    float* out = (float*)d_out;
    (void)in_sizes; (void)n_in; (void)out_size;

    if (ws_size >= (size_t)(112 * 128 * sizeof(__bf16))) {
        conv_A<<<dim3(56), dim3(256), 0, stream>>>(Amat, (__bf16*)d_ws);
        ca_main<true><<<dim3(BATCH / 64), dim3(256), 0, stream>>>(
            state, Amat, (const __bf16*)d_ws, target, out);
    } else {
        ca_main<false><<<dim3(BATCH / 64), dim3(256), 0, stream>>>(
            state, Amat, nullptr, target, out);
    }
}

// Round 8
// 71.557 us; speedup vs baseline: 1.5494x; 1.5494x over previous
//
#include <hip/hip_runtime.h>

#define DIMX 100
#define BATCH 131072
#define BUFW 108          // u16 stride: 216 B/row; all u16x4 accesses 8B-aligned

typedef __bf16 bf16x8 __attribute__((ext_vector_type(8)));
typedef __bf16 bf16x4 __attribute__((ext_vector_type(4)));
typedef float  f32x4  __attribute__((ext_vector_type(4)));

// ---- kernel 1: convert A (100x100 fp32) to zero-padded bf16 [112][128] in ws ----
__global__ void conv_A(const float* __restrict__ A, __bf16* __restrict__ ws) {
    int i = blockIdx.x * 256 + threadIdx.x;          // 112*128 = 14336
    if (i < 112 * 128) {
        int j = i >> 7, k = i & 127;
        float v = (j < DIMX && k < DIMX) ? A[j * DIMX + k] : 0.0f;
        ws[i] = (__bf16)v;
    }
}

// ---- main kernel: barrier-free; per-wave private bf16 LDS tile (16 rows) ----
// 128-thread blocks (2 waves): same per-wave work as the 71.6us R6 version,
// but 4096 blocks -> finer dispatch granularity -> higher average residency.
// R7 lesson: do NOT stage loads into big register arrays (spills: +120MB HBM).
// R5 lesson: do NOT clamp min-waves (VGPR 32 kills per-wave MLP).
template <bool USE_WS>
__global__ __launch_bounds__(128) void ca_main(
    const float* __restrict__ state, const float* __restrict__ Amat,
    const __bf16* __restrict__ Bws, const float* __restrict__ target,
    float* __restrict__ out)
{
    __shared__ __align__(16) __bf16 buf[2][16 * BUFW];  // 6912 B/block

    const int tid = threadIdx.x;
    const int wave = tid >> 6, lane = tid & 63;
    __bf16* __restrict__ wbuf = buf[wave];
    const long r0 = (long)blockIdx.x * 32 + wave * 16;   // wave's first row

    // ---- Phase A: coalesced sweep of the wave's 16 rows; base = -x+u*s -> LDS bf16 ----
#pragma unroll
    for (int it = 0; it < 7; ++it) {
        int i = lane + it * 64;
        if (i < 400) {                                   // 16 rows x 25 quads
            int row = i / 25, c4 = i - row * 25, j0 = c4 * 4;
            const float* rp = state + (r0 + row) * 400;
            f32x4 x = *reinterpret_cast<const f32x4*>(rp + j0);
            f32x4 e = *reinterpret_cast<const f32x4*>(rp + DIMX + j0);
            f32x4 w = *reinterpret_cast<const f32x4*>(rp + 3 * DIMX + j0);
            f32x4 t = *reinterpret_cast<const f32x4*>(target + j0);
            bf16x4 b;
#pragma unroll
            for (int q = 0; q < 4; ++q) {
                float u  = w[q] * (x[q] + e[q] - t[q]);
                float x2 = x[q] * x[q];
                float s  = x2 * __builtin_amdgcn_rcpf(1.0f + x2);
                b[q] = (__bf16)fmaf(u, s, -x[q]);
            }
            *reinterpret_cast<bf16x4*>(&wbuf[row * BUFW + j0]) = b;
        }
    }

    // ---- A-operand frags from global x (just read by this wave -> L1/L2-hot) ----
    const int fr = lane & 15, h = lane >> 4;
    const float* sp = state + (r0 + fr) * 400;
    bf16x8 afrag[4];
#pragma unroll
    for (int kt = 0; kt < 4; ++kt) {
        int k0 = kt * 32 + h * 8;
        bf16x8 f = {};
        if (k0 < DIMX) {
            f32x4 xa = *reinterpret_cast<const f32x4*>(sp + k0);
            f32x4 xb = *reinterpret_cast<const f32x4*>(sp + k0 + 4);
#pragma unroll
            for (int e = 0; e < 8; ++e) {
                float x = (e < 4) ? xa[e] : xb[e - 4];
                float x2 = x * x;
                float s = x2 * __builtin_amdgcn_rcpf(1.0f + x2);
                f[e] = (k0 + e < DIMX) ? (__bf16)s : (__bf16)0.0f;
            }
        }
        afrag[kt] = f;
    }

    // ---- MFMA over 7 N-tiles; epilogue: wbuf[row][j] = bf16(base + acc) ----
#pragma unroll
    for (int n = 0; n < 7; ++n) {
        f32x4 acc = {0.f, 0.f, 0.f, 0.f};
#pragma unroll
        for (int kt = 0; kt < 4; ++kt) {
            bf16x8 bf;
            if constexpr (USE_WS) {
                bf = *reinterpret_cast<const bf16x8*>(
                    Bws + (n * 16 + fr) * 128 + kt * 32 + h * 8);
            } else {
                int jj = n * 16 + fr;
#pragma unroll
                for (int e = 0; e < 8; ++e) {
                    int k = kt * 32 + h * 8 + e;
                    float v = (jj < DIMX && k < DIMX) ? Amat[jj * DIMX + k] : 0.0f;
                    bf[e] = (__bf16)v;
                }
            }
            acc = __builtin_amdgcn_mfma_f32_16x16x32_bf16(afrag[kt], bf, acc, 0, 0, 0);
        }
        int j = n * 16 + fr;
        if (j < DIMX) {
#pragma unroll
            for (int q = 0; q < 4; ++q) {
                int idx = (h * 4 + q) * BUFW + j;
                wbuf[idx] = (__bf16)((float)wbuf[idx] + acc[q]);
            }
        }
    }

    // ---- Phase B: contiguous nontemporal float4 writes of [dx,-dx,0,0] ----
#pragma unroll
    for (int it = 0; it < 25; ++it) {
        int i = lane + it * 64;                          // 16 rows x 100 quads
        int row = i / 100, c4 = i - row * 100;
        f32x4 v;
        if (c4 < 25) {
            bf16x4 d = *reinterpret_cast<const bf16x4*>(&wbuf[row * BUFW + c4 * 4]);
            v = f32x4{(float)d[0], (float)d[1], (float)d[2], (float)d[3]};
        } else if (c4 < 50) {
            bf16x4 d = *reinterpret_cast<const bf16x4*>(&wbuf[row * BUFW + c4 * 4 - DIMX]);
            v = f32x4{-(float)d[0], -(float)d[1], -(float)d[2], -(float)d[3]};
        } else {
            v = f32x4{0.f, 0.f, 0.f, 0.f};
        }
        __builtin_nontemporal_store(v,
            reinterpret_cast<f32x4*>(&out[(r0 + row) * 400 + c4 * 4]));
    }
}

extern "C" void kernel_launch(void* const* d_in, const int* in_sizes, int n_in,
                              void* d_out, int out_size, void* d_ws, size_t ws_size,
                              hipStream_t stream) {
    const float* state  = (const float*)d_in[0];
    const float* Amat   = (const float*)d_in[1];
    const float* target = (const float*)d_in[2];
    float* out = (float*)d_out;
    (void)in_sizes; (void)n_in; (void)out_size;

    if (ws_size >= (size_t)(112 * 128 * sizeof(__bf16))) {
        conv_A<<<dim3(56), dim3(256), 0, stream>>>(Amat, (__bf16*)d_ws);
        ca_main<true><<<dim3(BATCH / 32), dim3(128), 0, stream>>>(
            state, Amat, (const __bf16*)d_ws, target, out);
    } else {
        ca_main<false><<<dim3(BATCH / 32), dim3(128), 0, stream>>>(
            state, Amat, nullptr, target, out);
    }
}